// Round 1
// baseline (250.423 us; speedup 1.0000x reference)
//
#include <hip/hip_runtime.h>
#include <cstdint>
#include <cstddef>

#define ALPHA 0.01f
#define A1    0.99f
#define B_    8
#define S_    2048
#define H_    2048
#define NCH   8      // chunks along S
#define CL    256    // chunk length

typedef __attribute__((ext_vector_type(8))) short bf16x8;
typedef __attribute__((ext_vector_type(4))) float f32x4;

__device__ __forceinline__ unsigned short f2bf(float f) {
    unsigned int u = __float_as_uint(f);
    u += 0x7FFFu + ((u >> 16) & 1u);   // round-to-nearest-even
    return (unsigned short)(u >> 16);
}

__device__ __forceinline__ void gld16(const void* g, void* l) {
    __builtin_amdgcn_global_load_lds(
        (const __attribute__((address_space(1))) unsigned int*)g,
        (__attribute__((address_space(3))) unsigned int*)l, 16, 0, 0);
}

// ---------------- W cast: f32 -> bf16 ----------------
__global__ void ema_cast_w(const float* __restrict__ W, short* __restrict__ Wb) {
    int i = (blockIdx.x * 256 + threadIdx.x) * 4;
    float4 v = *(const float4*)(W + i);
    short4 o;
    o.x = (short)f2bf(v.x);
    o.y = (short)f2bf(v.y);
    o.z = (short)f2bf(v.z);
    o.w = (short)f2bf(v.w);
    *(short4*)(Wb + i) = o;
}

// ---------------- pass 1: chunk-local EMA carries ----------------
__global__ void ema_carry_kernel(const float* __restrict__ x, float* __restrict__ carry) {
    int bid = blockIdx.x;
    int hg = bid & 7;
    int c  = (bid >> 3) & 7;
    int b  = bid >> 6;
    int h  = hg * 256 + threadIdx.x;
    const float* px = x + ((size_t)(b * S_) + c * CL) * H_ + h;
    float s;
    int i0;
    if (c == 0) { s = px[0]; i0 = 1; }   // t=0 carries full weight
    else        { s = 0.f;   i0 = 0; }
    #pragma unroll 8
    for (int i = i0; i < CL; ++i)
        s = fmaf(A1, s, ALPHA * px[(size_t)i * H_]);
    carry[((b << 3) + c) * H_ + h] = s;
}

// ---------------- pass 2: apply carry-in, rescan, write bf16 s ----------------
__global__ void ema_apply_kernel(const float* __restrict__ x, const float* __restrict__ carry,
                                 unsigned short* __restrict__ sb) {
    int bid = blockIdx.x;
    int hg = bid & 7;
    int c  = (bid >> 3) & 7;
    int b  = bid >> 6;
    int h  = hg * 256 + threadIdx.x;

    float A256 = A1;                 // 0.99^(2^8) after 8 squarings
    #pragma unroll
    for (int q = 0; q < 8; ++q) A256 *= A256;

    float ci = 0.f, f = 1.f;
    for (int j = c - 1; j >= 0; --j) {
        ci = fmaf(carry[((b << 3) + j) * H_ + h], f, ci);
        f *= A256;
    }

    size_t base = ((size_t)(b * S_) + c * CL) * H_ + h;
    const float* px = x + base;
    unsigned short* ps = sb + base;
    float s;
    int i0;
    if (c == 0) { s = px[0]; ps[0] = f2bf(s); i0 = 1; }
    else        { s = ci;    i0 = 0; }
    #pragma unroll 8
    for (int i = i0; i < CL; ++i) {
        s = fmaf(A1, s, ALPHA * px[(size_t)i * H_]);
        ps[(size_t)i * H_] = f2bf(s);
    }
}

// ---------------- GEMM: out[m,n] = sum_k s[m,k]*W[n,k] + bias[n] ----------------
// m97 structure: 128x128 tile, BK=32, 4 waves (2x2), 16x16x32 bf16 MFMA,
// global_load_lds width-16 staging, linear LDS.
__global__ __launch_bounds__(256) void ema_gemm_kernel(
        const short* __restrict__ Sb, const short* __restrict__ Wb,
        const float* __restrict__ bias, float* __restrict__ out) {
    __shared__ alignas(16) short lA[128 * 32];
    __shared__ alignas(16) short lB[128 * 32];

    int bid = blockIdx.x;                 // 2048 blocks
    int swz = ((bid & 7) << 8) | (bid >> 3);   // XCD swizzle, bijective (2048 % 8 == 0)
    int tm = swz >> 4;                    // 0..127  (M / 128)
    int tn = swz & 15;                    // 0..15   (N / 128)

    int tid  = threadIdx.x;
    int lane = tid & 63;
    int wid  = tid >> 6;
    int wm   = wid >> 1;                  // 0..1
    int wn   = wid & 1;                   // 0..1

    int rowA = tm << 7;
    int rowB = tn << 7;

    // staging: 128x32 bf16 tile = 8192B; 256 threads * 16B = 4096B per round, 2 rounds
    int i0 = tid, i1 = tid + 256;
    const short* gA0 = Sb + ((size_t)(rowA + (i0 >> 2)) << 11) + ((i0 & 3) << 3);
    const short* gA1 = Sb + ((size_t)(rowA + (i1 >> 2)) << 11) + ((i1 & 3) << 3);
    const short* gB0 = Wb + ((size_t)(rowB + (i0 >> 2)) << 11) + ((i0 & 3) << 3);
    const short* gB1 = Wb + ((size_t)(rowB + (i1 >> 2)) << 11) + ((i1 & 3) << 3);
    // wave-uniform LDS destinations (HW writes base + lane*16)
    short* dA0 = &lA[(size_t)wid * 512];
    short* dA1 = &lA[2048 + (size_t)wid * 512];
    short* dB0 = &lB[(size_t)wid * 512];
    short* dB1 = &lB[2048 + (size_t)wid * 512];

    f32x4 acc[4][4];
    #pragma unroll
    for (int i = 0; i < 4; ++i)
        #pragma unroll
        for (int j = 0; j < 4; ++j)
            acc[i][j] = (f32x4){0.f, 0.f, 0.f, 0.f};

    // fragment read offsets (A: row = wm*64 + i*16 + (lane&15), k = (lane>>4)*8)
    int aoff = ((wm << 6) + (lane & 15)) * 32 + ((lane >> 4) << 3);
    int boff = ((wn << 6) + (lane & 15)) * 32 + ((lane >> 4) << 3);

    for (int kt = 0; kt < 64; ++kt) {
        int ko = kt << 5;
        gld16(gA0 + ko, dA0);
        gld16(gA1 + ko, dA1);
        gld16(gB0 + ko, dB0);
        gld16(gB1 + ko, dB1);
        asm volatile("s_waitcnt vmcnt(0)" ::: "memory");
        __syncthreads();

        bf16x8 af[4], bfr[4];
        #pragma unroll
        for (int i = 0; i < 4; ++i) af[i] = *(const bf16x8*)&lA[aoff + i * 512];
        #pragma unroll
        for (int j = 0; j < 4; ++j) bfr[j] = *(const bf16x8*)&lB[boff + j * 512];

        #pragma unroll
        for (int i = 0; i < 4; ++i)
            #pragma unroll
            for (int j = 0; j < 4; ++j)
                acc[i][j] = __builtin_amdgcn_mfma_f32_16x16x32_bf16(af[i], bfr[j], acc[i][j], 0, 0, 0);
        __syncthreads();
    }

    // epilogue: D row = (lane>>4)*4 + q, col = lane&15 (verified m89/m91 layout)
    int colbase = rowB + (wn << 6) + (lane & 15);
    int rowbase = rowA + (wm << 6) + ((lane >> 4) << 2);
    float bb[4];
    #pragma unroll
    for (int j = 0; j < 4; ++j) bb[j] = bias[colbase + j * 16];
    #pragma unroll
    for (int i = 0; i < 4; ++i) {
        int r = rowbase + i * 16;
        #pragma unroll
        for (int j = 0; j < 4; ++j) {
            int ccol = colbase + j * 16;
            #pragma unroll
            for (int q = 0; q < 4; ++q)
                out[((size_t)(r + q) << 11) + ccol] = acc[i][j][q] + bb[j];
        }
    }
}

extern "C" void kernel_launch(void* const* d_in, const int* in_sizes, int n_in,
                              void* d_out, int out_size, void* d_ws, size_t ws_size,
                              hipStream_t stream) {
    const float* x    = (const float*)d_in[0];   // [B,S,H] f32
    const float* W    = (const float*)d_in[1];   // [H,H] f32
    const float* bias = (const float*)d_in[2];   // [H] f32
    float* out = (float*)d_out;                  // [B,S,H] f32

    char* ws = (char*)d_ws;
    size_t s_bytes = (size_t)B_ * S_ * H_ * 2;   // 67.1 MB bf16 s
    size_t w_bytes = (size_t)H_ * H_ * 2;        // 8.4 MB bf16 W
    unsigned short* s_bf = (unsigned short*)ws;
    short*          w_bf = (short*)(ws + s_bytes);
    float*          carry = (float*)(ws + s_bytes + w_bytes);  // 8*8*2048 f32

    ema_cast_w<<<(H_ * H_) / 1024, 256, 0, stream>>>(W, w_bf);
    ema_carry_kernel<<<B_ * NCH * (H_ / 256), 256, 0, stream>>>(x, carry);
    ema_apply_kernel<<<B_ * NCH * (H_ / 256), 256, 0, stream>>>(x, carry, s_bf);
    ema_gemm_kernel<<<(16384 / 128) * (2048 / 128), 256, 0, stream>>>(
        (const short*)s_bf, w_bf, bias, out);
}

// Round 2
// 211.900 us; speedup vs baseline: 1.1818x; 1.1818x over previous
//
#include <hip/hip_runtime.h>
#include <cstdint>
#include <cstddef>

#define ALPHA 0.01f
#define A1    0.99f
#define B_    8
#define S_    2048
#define H_    2048
#define NCH   8      // chunks along S
#define CL    256    // chunk length
#define NKT   32     // K tiles in GEMM (2048/64)

typedef __attribute__((ext_vector_type(8))) short bf16x8;
typedef __attribute__((ext_vector_type(4))) float f32x4;

__device__ __forceinline__ unsigned short f2bf(float f) {
    unsigned int u = __float_as_uint(f);
    u += 0x7FFFu + ((u >> 16) & 1u);   // round-to-nearest-even
    return (unsigned short)(u >> 16);
}

__device__ __forceinline__ void gld16(const void* g, void* l) {
    __builtin_amdgcn_global_load_lds(
        (const __attribute__((address_space(1))) unsigned int*)g,
        (__attribute__((address_space(3))) unsigned int*)l, 16, 0, 0);
}

// ---------------- W cast: f32 -> bf16 ----------------
__global__ void ema_cast_w(const float* __restrict__ W, short* __restrict__ Wb) {
    int i = (blockIdx.x * 256 + threadIdx.x) * 4;
    float4 v = *(const float4*)(W + i);
    short4 o;
    o.x = (short)f2bf(v.x);
    o.y = (short)f2bf(v.y);
    o.z = (short)f2bf(v.z);
    o.w = (short)f2bf(v.w);
    *(short4*)(Wb + i) = o;
}

// ---------------- pass 1: chunk-local EMA carries ----------------
__global__ void ema_carry_kernel(const float* __restrict__ x, float* __restrict__ carry) {
    int bid = blockIdx.x;
    int hg = bid & 7;
    int c  = (bid >> 3) & 7;
    int b  = bid >> 6;
    int h  = hg * 256 + threadIdx.x;
    const float* px = x + ((size_t)(b * S_) + c * CL) * H_ + h;
    float s;
    int i0;
    if (c == 0) { s = px[0]; i0 = 1; }   // t=0 carries full weight
    else        { s = 0.f;   i0 = 0; }
    #pragma unroll 8
    for (int i = i0; i < CL; ++i)
        s = fmaf(A1, s, ALPHA * px[(size_t)i * H_]);
    carry[((b << 3) + c) * H_ + h] = s;
}

// ---------------- pass 2: apply carry-in, rescan, write bf16 s ----------------
__global__ void ema_apply_kernel(const float* __restrict__ x, const float* __restrict__ carry,
                                 unsigned short* __restrict__ sb) {
    int bid = blockIdx.x;
    int hg = bid & 7;
    int c  = (bid >> 3) & 7;
    int b  = bid >> 6;
    int h  = hg * 256 + threadIdx.x;

    float A256 = A1;                 // 0.99^(2^8) after 8 squarings
    #pragma unroll
    for (int q = 0; q < 8; ++q) A256 *= A256;

    float ci = 0.f, f = 1.f;
    for (int j = c - 1; j >= 0; --j) {
        ci = fmaf(carry[((b << 3) + j) * H_ + h], f, ci);
        f *= A256;
    }

    size_t base = ((size_t)(b * S_) + c * CL) * H_ + h;
    const float* px = x + base;
    unsigned short* ps = sb + base;
    float s;
    int i0;
    if (c == 0) { s = px[0]; ps[0] = f2bf(s); i0 = 1; }
    else        { s = ci;    i0 = 0; }
    #pragma unroll 8
    for (int i = i0; i < CL; ++i) {
        s = fmaf(A1, s, ALPHA * px[(size_t)i * H_]);
        ps[(size_t)i * H_] = f2bf(s);
    }
}

// ---------------- GEMM: 256x256 tile, BK=64, 8 waves, 8-phase counted-vmcnt ----
// out[m,n] = sum_k s[m,k]*W[n,k] + bias[n].  M=16384 N=2048 K=2048.
// LDS 128 KiB: A,B double-buffered 256x64 bf16 tiles.
// A storage quarter order [Q0,Q2,Q1,Q3]; B storage: 32-row slices grouped
// [nh0: s0,s2,s4,s6][nh1: s1,s3,s5,s7] so staging regions match phase liveness.
// Swizzle: byte ^= ((storage_row & 7) << 4); applied on global source (stage)
// and ds_read address (both-sides rule).

#define BAR __builtin_amdgcn_s_barrier()
#define WAIT_LGKM do { asm volatile("s_waitcnt lgkmcnt(0)" ::: "memory"); \
                       __builtin_amdgcn_sched_barrier(0); } while (0)
#define VMW(n) asm volatile("s_waitcnt vmcnt(" #n ")" ::: "memory")

#define STGA(i, kt, buf) gld16(gA[i] + (size_t)(kt) * 128, &ldsA[buf][((i) << 12) + (w << 9)])
#define STGB(i, kt, buf) gld16(gB[i] + (size_t)(kt) * 128, &ldsB[buf][((i) << 12) + (w << 9)])

#define LDA(mh) do { int ra_ = (wm << 1) | (mh);                                   \
    const char* base_ = (const char*)&ldsA[cur][0]                                 \
        + (((((ra_ & 1) << 1) | (ra_ >> 1))) << 13) + laneRow;                     \
    _Pragma("unroll") for (int m_ = 0; m_ < 4; ++m_) {                             \
        Af[m_][0] = *(const bf16x8*)(base_ + (m_ << 11) + ck0);                    \
        Af[m_][1] = *(const bf16x8*)(base_ + (m_ << 11) + ck1); } } while (0)

#define LDB(nh) do { const char* base_ = (const char*)&ldsB[cur][0]                \
        + ((nh) << 14) + (wn << 12) + laneRow;                                     \
    _Pragma("unroll") for (int n_ = 0; n_ < 2; ++n_) {                             \
        Bf[(nh) * 2 + n_][0] = *(const bf16x8*)(base_ + (n_ << 11) + ck0);         \
        Bf[(nh) * 2 + n_][1] = *(const bf16x8*)(base_ + (n_ << 11) + ck1); } } while (0)

#define MM(mh, nh) do { __builtin_amdgcn_s_setprio(1);                             \
    _Pragma("unroll") for (int m_ = 0; m_ < 4; ++m_)                               \
    _Pragma("unroll") for (int n_ = 0; n_ < 2; ++n_)                               \
    _Pragma("unroll") for (int k_ = 0; k_ < 2; ++k_)                               \
        acc[(mh) * 4 + m_][(nh) * 2 + n_] = __builtin_amdgcn_mfma_f32_16x16x32_bf16( \
            Af[m_][k_], Bf[(nh) * 2 + n_][k_], acc[(mh) * 4 + m_][(nh) * 2 + n_], 0, 0, 0); \
    __builtin_amdgcn_s_setprio(0); } while (0)

__global__ __launch_bounds__(512, 2) void ema_gemm_kernel(
        const short* __restrict__ Sb, const short* __restrict__ Wb,
        const float* __restrict__ bias, float* __restrict__ out) {
    __shared__ short ldsA[2][16384];   // 64 KiB
    __shared__ short ldsB[2][16384];   // 64 KiB

    int bid = blockIdx.x;
    int swz = ((bid & 7) << 6) | (bid >> 3);   // XCD swizzle, bijective (512 % 8 == 0)
    int tm = swz >> 3;                 // 0..63
    int tn = swz & 7;                  // 0..7

    int tid  = threadIdx.x;
    int lane = tid & 63;
    int w    = tid >> 6;               // 0..7
    int wm   = w >> 2;                 // 0..1
    int wn   = w & 3;                  // 0..3

    const int K2 = H_ * 2;             // row stride in bytes (4096)
    int rowA = tm << 8;
    int rowB = tn << 8;

    // ---- staging source pointers (per-lane, pre-swizzled global addresses) ----
    int rowoff = (w << 3) + (lane >> 3);                 // 0..63 within an 8KB issue
    int colb   = (((lane & 7) ^ (lane >> 3)) << 4);      // inverse-swizzled k-byte
    const char* SbB = (const char*)Sb;
    const char* WbB = (const char*)Wb;
    const char* gA[4];
    const char* gB[4];
    #pragma unroll
    for (int i = 0; i < 4; ++i) {
        int lq = ((i & 1) << 1) | (i >> 1);              // storage slot -> logical A quarter
        gA[i] = SbB + (size_t)(rowA + lq * 64 + rowoff) * K2 + colb;
        int pos = 2 * i + (w >> 2);                      // B storage 32-row slot
        int ls  = ((pos & 3) << 1) | (pos >> 2);         // -> logical slice
        gB[i] = WbB + (size_t)(rowB + ls * 32 + ((w & 3) << 3) + (lane >> 3)) * K2 + colb;
    }

    // ---- fragment ds_read offsets (swizzled) ----
    int laneRow = (lane & 15) << 7;
    int ck0 = (((lane >> 4)) ^ (lane & 7)) << 4;
    int ck1 = ((4 + (lane >> 4)) ^ (lane & 7)) << 4;

    f32x4 acc[8][4];
    #pragma unroll
    for (int i = 0; i < 8; ++i)
        #pragma unroll
        for (int j = 0; j < 4; ++j)
            acc[i][j] = (f32x4){0.f, 0.f, 0.f, 0.f};
    bf16x8 Af[4][2], Bf[4][2];

    int colg = (tn << 8) + (wn << 6) + (lane & 15);
    float bb[4];
    #pragma unroll
    for (int n = 0; n < 4; ++n) bb[n] = bias[colg + (n << 4)];

    // ---- prologue: tile0 full + tile1 first halves; leave 6 loads in flight ----
    STGA(0, 0, 0); STGA(1, 0, 0); STGB(0, 0, 0); STGB(1, 0, 0);   // A1st(0), B1st(0)
    STGA(2, 0, 0); STGA(3, 0, 0); STGB(2, 0, 0); STGB(3, 0, 0);   // A2nd(0), B2nd(0)
    STGA(0, 1, 1); STGA(1, 1, 1); STGB(0, 1, 1); STGB(1, 1, 1);   // A1st(1), B1st(1)
    VMW(6);
    BAR;

    for (int t = 0; t < NKT; ++t) {
        int cur = t & 1, nxt = cur ^ 1;
        bool i01 = (t < NKT - 1), i23 = (t < NKT - 2);
        // phase 0: compute (mh0,nh0); stage A2nd(t+1)
        LDA(0); LDB(0);
        if (i01) { STGA(2, t + 1, nxt); STGA(3, t + 1, nxt); }
        BAR; WAIT_LGKM;
        MM(0, 0);
        if (i01) { VMW(6); }
        BAR;
        // phase 1: compute (mh0,nh1); stage B2nd(t+1)
        LDB(1);
        if (i01) { STGB(2, t + 1, nxt); STGB(3, t + 1, nxt); }
        BAR; WAIT_LGKM;
        MM(0, 1);
        BAR;
        // phase 2: compute (mh1,nh0); stage A1st(t+2) into dead quarters of cur
        LDA(1);
        if (i23) { STGA(0, t + 2, cur); STGA(1, t + 2, cur); }
        BAR; WAIT_LGKM;
        MM(1, 0);
        BAR;
        // phase 3: compute (mh1,nh1); stage B1st(t+2) into dead slices of cur
        if (i23) { STGB(0, t + 2, cur); STGB(1, t + 2, cur); }
        BAR;
        MM(1, 1);
        if (t == NKT - 2) { VMW(0); }          // entering last tile: drain
        else if (t < NKT - 2) { VMW(6); }      // steady state: 3 half-tiles in flight
        BAR;
    }

    // ---- epilogue: C/D layout col=lane&15, row=(lane>>4)*4+q ----
    int rowg = (tm << 8) + (wm << 7) + ((lane >> 4) << 2);
    #pragma unroll
    for (int m = 0; m < 8; ++m) {
        #pragma unroll
        for (int n = 0; n < 4; ++n) {
            int c = colg + (n << 4);
            size_t rb = (size_t)(rowg + (m << 4)) << 11;
            #pragma unroll
            for (int q = 0; q < 4; ++q)
                out[rb + ((size_t)q << 11) + c] = acc[m][n][q] + bb[n];
        }
    }
}

extern "C" void kernel_launch(void* const* d_in, const int* in_sizes, int n_in,
                              void* d_out, int out_size, void* d_ws, size_t ws_size,
                              hipStream_t stream) {
    const float* x    = (const float*)d_in[0];   // [B,S,H] f32
    const float* W    = (const float*)d_in[1];   // [H,H] f32
    const float* bias = (const float*)d_in[2];   // [H] f32
    float* out = (float*)d_out;                  // [B,S,H] f32

    char* ws = (char*)d_ws;
    size_t s_bytes = (size_t)B_ * S_ * H_ * 2;   // 67.1 MB bf16 s
    size_t w_bytes = (size_t)H_ * H_ * 2;        // 8.4 MB bf16 W
    unsigned short* s_bf = (unsigned short*)ws;
    short*          w_bf = (short*)(ws + s_bytes);
    float*          carry = (float*)(ws + s_bytes + w_bytes);  // 8*8*2048 f32

    ema_cast_w<<<(H_ * H_) / 1024, 256, 0, stream>>>(W, w_bf);
    ema_carry_kernel<<<B_ * NCH * (H_ / 256), 256, 0, stream>>>(x, carry);
    ema_apply_kernel<<<B_ * NCH * (H_ / 256), 256, 0, stream>>>(x, carry, s_bf);
    ema_gemm_kernel<<<(16384 / 256) * (2048 / 256), 512, 0, stream>>>(
        (const short*)s_bf, w_bf, bias, out);
}